// Round 11
// baseline (3733.689 us; speedup 1.0000x reference)
//
#include <hip/hip_runtime.h>

#define TT 4000   // timesteps
#define HH 64     // hidden
#define NBATCH 16 // batch elems per block
#define NBLK 16   // blocks (16 x 16 = 256 batch)
#define EE 128    // fc out
#define CH 500    // x-chunk staged in LDS
#define XSTR (CH + 1)
#define HSTR 136  // padded k-stride of h LDS (128 + 8) -> conflict-free B reads

typedef __attribute__((ext_vector_type(8))) _Float16 f16x8;
typedef __attribute__((ext_vector_type(4))) float    f32x4;
typedef __attribute__((ext_vector_type(4))) int      i32x4;

__device__ __forceinline__ float fsig(float x) {
    return __builtin_amdgcn_rcpf(1.f + __expf(-x));
}
__device__ __forceinline__ float ftanh_(float x) {
    return fmaf(2.f, __builtin_amdgcn_rcpf(1.f + __expf(-2.f * x)), -1.f);
}

// 8 consecutive global floats -> packed f16x8, returned as i32x4 for fencing.
__device__ __forceinline__ i32x4 ld8h(const float* p) {
    float4 a = ((const float4*)p)[0];
    float4 b = ((const float4*)p)[1];
    f16x8 h = f16x8{(_Float16)a.x, (_Float16)a.y, (_Float16)a.z, (_Float16)a.w,
                    (_Float16)b.x, (_Float16)b.y, (_Float16)b.z, (_Float16)b.w};
    return (i32x4)h;   // same-size vector cast = bitcast
}

#define MFMA(A, B, C) __builtin_amdgcn_mfma_f32_16x16x32_f16((f16x8)(A), (B), (C), 0, 0, 0)

// 16 blocks x 1024 thr; block = 16 batch columns. gates[256,16] = W'.h[.,16]
// via mfma_f32_16x16x32_f16. Weight rows PRE-PERMUTED m = 4n + gate, so with
// C/D layout (col=lane&15=batch, row=quad*4+reg) each lane's 4 C-regs are the
// 4 gates (i,f,g,o) of one (n,batch) -> cell update fully in-register, no
// gate LDS round trip, ONE barrier/step.
//   waves 0-7 : L0 tiles (k=64, 2 ksteps), gates0(t) from h0(t-1)
//   waves 8-15: L1 tiles (k=128 cat[h0|h1], 4 ksteps), gates1(t-1)
// (the R3-R10-verified layer pipeline). h fp16, double-buffered.
//
// R10 lesson: allocator refuses >~64 VGPR of pinned state -> A-fragments are
// parked in AGPRs ("+a" fence); gfx950 mfma reads A/B from AGPR directly.
// DS/step: ~48 B-frag b128 (vs 1024 read-equivalents for 16 batches in the
// persistent-wave design) + 32 b16 h-writes + x reads ~= 650 cyc.
__global__ __launch_bounds__(1024, 2)
void lstm2_fc_kernel(const float* __restrict__ x,      // [B, T, 1]
                     const float* __restrict__ W_ih0,  // [256, 1]
                     const float* __restrict__ W_hh0,  // [256, 64]
                     const float* __restrict__ b_ih0,  // [256]
                     const float* __restrict__ b_hh0,  // [256]
                     const float* __restrict__ W_ih1,  // [256, 64]
                     const float* __restrict__ W_hh1,  // [256, 64]
                     const float* __restrict__ b_ih1,  // [256]
                     const float* __restrict__ b_hh1,  // [256]
                     const float* __restrict__ W_fc,   // [128, 64]
                     const float* __restrict__ b_fc,   // [128]
                     float* __restrict__ out)          // [B, 128]
{
    const int tid  = threadIdx.x;
    const int lane = tid & 63;
    const int wid  = tid >> 6;        // 0..15
    const int quad = lane >> 4;       // 0..3
    const int l16  = lane & 15;       // batch col (B/C/D n); A-operand m
    const int b0   = blockIdx.x * NBATCH;

    __shared__ __align__(16) float    x_s[NBATCH][XSTR];
    __shared__ __align__(16) _Float16 hbuf[2][NBATCH][HSTR];  // k: [0,64)=h0, [64,128)=h1

    for (int i = tid; i < 2 * NBATCH * HSTR; i += 1024)
        ((_Float16*)hbuf)[i] = (_Float16)0.f;

    const bool isL0 = (wid < 8);
    const int  tw   = isL0 ? wid : wid - 8;    // 0..7; tiles Tm = 2tw, 2tw+1
    // A-operand row: m = Tm*16 + l16; permuted orig row r = (m&3)*64 + (m>>2).
    const int r0 = (l16 & 3) * 64 + (2 * tw) * 4 + (l16 >> 2);     // tile 0
    const int r1 = (l16 & 3) * 64 + (2 * tw + 1) * 4 + (l16 >> 2); // tile 1
    const int k8 = quad * 8;          // A k-offset within a 32-wide kstep

    i32x4 F0, F1, F2, F3, F4, F5, F6, F7;
    if (isL0) {           // L0: W_hh0, ksteps {0,1} per tile
        F0 = ld8h(W_hh0 + r0 * 64 + 0  + k8);
        F1 = ld8h(W_hh0 + r0 * 64 + 32 + k8);
        F2 = ld8h(W_hh0 + r1 * 64 + 0  + k8);
        F3 = ld8h(W_hh0 + r1 * 64 + 32 + k8);
        F4 = F0; F5 = F1; F6 = F2; F7 = F3;    // keep reg shape uniform
    } else {              // L1: k-cat [W_ih1 | W_hh1], ksteps {0..3} per tile
        F0 = ld8h(W_ih1 + r0 * 64 + 0  + k8);
        F1 = ld8h(W_ih1 + r0 * 64 + 32 + k8);
        F2 = ld8h(W_hh1 + r0 * 64 + 0  + k8);
        F3 = ld8h(W_hh1 + r0 * 64 + 32 + k8);
        F4 = ld8h(W_ih1 + r1 * 64 + 0  + k8);
        F5 = ld8h(W_ih1 + r1 * 64 + 32 + k8);
        F6 = ld8h(W_hh1 + r1 * 64 + 0  + k8);
        F7 = ld8h(W_hh1 + r1 * 64 + 32 + k8);
    }

    // C-init constants: C rows m = Tm*16 + quad*4 + g -> orig r = g*64 + n,
    // n = Tm*4 + quad. Reg g == gate g (PyTorch i,f,g,o).
    const int n0 = (2 * tw) * 4 + quad;        // cell n, tile 0
    const int n1 = (2 * tw + 1) * 4 + quad;    // tile 1
    f32x4 Bi0, Bi1, Wx0, Wx1;
    if (isL0) {
        Bi0 = f32x4{b_ih0[n0] + b_hh0[n0],           b_ih0[64 + n0] + b_hh0[64 + n0],
                    b_ih0[128 + n0] + b_hh0[128 + n0], b_ih0[192 + n0] + b_hh0[192 + n0]};
        Bi1 = f32x4{b_ih0[n1] + b_hh0[n1],           b_ih0[64 + n1] + b_hh0[64 + n1],
                    b_ih0[128 + n1] + b_hh0[128 + n1], b_ih0[192 + n1] + b_hh0[192 + n1]};
        Wx0 = f32x4{W_ih0[n0], W_ih0[64 + n0], W_ih0[128 + n0], W_ih0[192 + n0]};
        Wx1 = f32x4{W_ih0[n1], W_ih0[64 + n1], W_ih0[128 + n1], W_ih0[192 + n1]};
    } else {
        Bi0 = f32x4{b_ih1[n0] + b_hh1[n0],           b_ih1[64 + n0] + b_hh1[64 + n0],
                    b_ih1[128 + n0] + b_hh1[128 + n0], b_ih1[192 + n0] + b_hh1[192 + n0]};
        Bi1 = f32x4{b_ih1[n1] + b_hh1[n1],           b_ih1[64 + n1] + b_hh1[64 + n1],
                    b_ih1[128 + n1] + b_hh1[128 + n1], b_ih1[192 + n1] + b_hh1[192 + n1]};
        Wx0 = f32x4{0.f, 0.f, 0.f, 0.f};
        Wx1 = Wx0;
    }

    // Park A-fragments in AGPRs (remat/spill fence); biases stay VGPR.
    asm volatile("" : "+a"(F0), "+a"(F1), "+a"(F2), "+a"(F3),
                      "+a"(F4), "+a"(F5), "+a"(F6), "+a"(F7));
    asm volatile("" : "+v"(Bi0), "+v"(Bi1), "+v"(Wx0), "+v"(Wx1));

    float cA = 0.f, cB = 0.f;   // cell state: (n0,l16) and (n1,l16) of my layer

    __syncthreads();

    for (int t = 0; t <= TT; ++t) {
        if ((t % CH) == 0 && t < TT) {           // stage x chunk (uniform)
            for (int u = lane; u < CH; u += 64)
                x_s[wid][u] = x[(size_t)(b0 + wid) * TT + t + u];
            __syncthreads();
        }
        const _Float16* hb = &hbuf[t & 1][0][0];
        _Float16*       hw = &hbuf[(t + 1) & 1][0][0];
        const int bo = l16 * HSTR + k8;          // B-frag: n=l16(batch), k=quad*8+j

        if (isL0) {
            f16x8 Bf0 = *(const f16x8*)(hb + bo);        // h0 k 0..31
            f16x8 Bf1 = *(const f16x8*)(hb + bo + 32);   // h0 k 32..63
            float xt = (t < TT) ? x_s[l16][t % CH] : 0.f;
            f32x4 c0 = f32x4{fmaf(Wx0[0], xt, Bi0[0]), fmaf(Wx0[1], xt, Bi0[1]),
                             fmaf(Wx0[2], xt, Bi0[2]), fmaf(Wx0[3], xt, Bi0[3])};
            f32x4 c1 = f32x4{fmaf(Wx1[0], xt, Bi1[0]), fmaf(Wx1[1], xt, Bi1[1]),
                             fmaf(Wx1[2], xt, Bi1[2]), fmaf(Wx1[3], xt, Bi1[3])};
            c0 = MFMA(F0, Bf0, c0); c0 = MFMA(F1, Bf1, c0);
            c1 = MFMA(F2, Bf0, c1); c1 = MFMA(F3, Bf1, c1);
            if (t < TT) {                        // L0 cell, time t
                float iv = fsig(c0[0]), fv = fsig(c0[1]);
                float gv = ftanh_(c0[2]), ov = fsig(c0[3]);
                cA = fmaf(fv, cA, iv * gv);
                hw[l16 * HSTR + n0] = (_Float16)(ov * ftanh_(cA));
                iv = fsig(c1[0]); fv = fsig(c1[1]);
                gv = ftanh_(c1[2]); ov = fsig(c1[3]);
                cB = fmaf(fv, cB, iv * gv);
                hw[l16 * HSTR + n1] = (_Float16)(ov * ftanh_(cB));
            }
        } else {
            f16x8 Bf0 = *(const f16x8*)(hb + bo);        // h0 k 0..31
            f16x8 Bf1 = *(const f16x8*)(hb + bo + 32);   // h0 k 32..63
            f16x8 Bf2 = *(const f16x8*)(hb + bo + 64);   // h1 k 0..31
            f16x8 Bf3 = *(const f16x8*)(hb + bo + 96);   // h1 k 32..63
            f32x4 c0 = f32x4{Bi0[0], Bi0[1], Bi0[2], Bi0[3]};
            f32x4 c1 = f32x4{Bi1[0], Bi1[1], Bi1[2], Bi1[3]};
            c0 = MFMA(F0, Bf0, c0); c0 = MFMA(F1, Bf1, c0);
            c0 = MFMA(F2, Bf2, c0); c0 = MFMA(F3, Bf3, c0);
            c1 = MFMA(F4, Bf0, c1); c1 = MFMA(F5, Bf1, c1);
            c1 = MFMA(F6, Bf2, c1); c1 = MFMA(F7, Bf3, c1);
            if (t > 0) {                         // L1 cell, time t-1
                float iv = fsig(c0[0]), fv = fsig(c0[1]);
                float gv = ftanh_(c0[2]), ov = fsig(c0[3]);
                cA = fmaf(fv, cA, iv * gv);
                hw[l16 * HSTR + 64 + n0] = (_Float16)(ov * ftanh_(cA));
                iv = fsig(c1[0]); fv = fsig(c1[1]);
                gv = ftanh_(c1[2]); ov = fsig(c1[3]);
                cB = fmaf(fv, cB, iv * gv);
                hw[l16 * HSTR + 64 + n1] = (_Float16)(ov * ftanh_(cB));
            }
        }
        __syncthreads();                         // h exchange (double-buffered)
    }

    // FC on h1(TT-1), in hbuf[(TT+1)&1][batch][64..128). 2048 outs, 2/thread.
    {
        const _Float16* h1f = &hbuf[(TT + 1) & 1][0][0];
        const int e  = tid & 127;
        const int bp = tid >> 7;                 // 0..7 -> batches bp, bp+8
        const float4* wf = (const float4*)(W_fc + e * HH);
        const _Float16* ha = h1f + bp * HSTR + 64;
        const _Float16* hc = h1f + (bp + 8) * HSTR + 64;
        float acc0 = b_fc[e], acc1 = b_fc[e];
        #pragma unroll
        for (int k4 = 0; k4 < HH / 4; ++k4) {
            float4 w = wf[k4];
            acc0 = fmaf(w.x, (float)ha[4*k4+0], acc0);
            acc0 = fmaf(w.y, (float)ha[4*k4+1], acc0);
            acc0 = fmaf(w.z, (float)ha[4*k4+2], acc0);
            acc0 = fmaf(w.w, (float)ha[4*k4+3], acc0);
            acc1 = fmaf(w.x, (float)hc[4*k4+0], acc1);
            acc1 = fmaf(w.y, (float)hc[4*k4+1], acc1);
            acc1 = fmaf(w.z, (float)hc[4*k4+2], acc1);
            acc1 = fmaf(w.w, (float)hc[4*k4+3], acc1);
        }
        out[(size_t)(b0 + bp) * EE + e] = acc0;
        out[(size_t)(b0 + bp + 8) * EE + e] = acc1;
    }
}

extern "C" void kernel_launch(void* const* d_in, const int* in_sizes, int n_in,
                              void* d_out, int out_size, void* d_ws, size_t ws_size,
                              hipStream_t stream) {
    const float* x     = (const float*)d_in[0];
    const float* W_ih0 = (const float*)d_in[1];
    const float* W_hh0 = (const float*)d_in[2];
    const float* b_ih0 = (const float*)d_in[3];
    const float* b_hh0 = (const float*)d_in[4];
    const float* W_ih1 = (const float*)d_in[5];
    const float* W_hh1 = (const float*)d_in[6];
    const float* b_ih1 = (const float*)d_in[7];
    const float* b_hh1 = (const float*)d_in[8];
    const float* W_fc  = (const float*)d_in[9];
    const float* b_fc  = (const float*)d_in[10];
    float* out = (float*)d_out;

    lstm2_fc_kernel<<<dim3(NBLK), dim3(1024), 0, stream>>>(
        x, W_ih0, W_hh0, b_ih0, b_hh0, W_ih1, W_hh1, b_ih1, b_hh1, W_fc, b_fc, out);
}

// Round 14
// 1967.763 us; speedup vs baseline: 1.8974x; 1.8974x over previous
//
#include <hip/hip_runtime.h>

#define TT 4000   // timesteps
#define HH 64     // hidden
#define NB 256    // batch
#define EE 128    // fc out

typedef __attribute__((ext_vector_type(2))) _Float16 h2;
typedef __attribute__((ext_vector_type(8))) _Float16 h8;

__device__ __forceinline__ float ftanh(float x) {
    return fmaf(2.f, __builtin_amdgcn_rcpf(1.f + __expf(-2.f * x)), -1.f);
}

#if __has_builtin(__builtin_amdgcn_fdot2)
#define FDOT2(a, b, c) __builtin_amdgcn_fdot2((a), (b), (c), false)
#else
#define FDOT2(a, b, c) fmaf((float)(a).x, (float)(b).x, fmaf((float)(a).y, (float)(b).y, (c)))
#endif

// h2 sub-extract from h8 register (sub-register addressing, no memory).
#define H2V(V, i) (__builtin_shufflevector((V), (V), 2 * (i), 2 * (i) + 1))

// DPP helpers (VALU pipe, no LDS). ctrl must be an ICE -> template param.
template <int CTRL>
__device__ __forceinline__ float dpp_mov(float v) {
    return __int_as_float(__builtin_amdgcn_update_dpp(
        0, __float_as_int(v), CTRL, 0xF, 0xF, true));
}
#define DPP_XOR1 0xB1   // quad_perm [1,0,3,2]  (flip s)      [HW-verified R8/R9]
#define DPP_XOR2 0x4E   // quad_perm [2,3,0,1]  (flip u)      [HW-verified R8/R9]
#define DPP_FB   0x44   // quad_perm [0,1,0,1]  (broadcast u=0 per s)
#define DPP_OB   0xEE   // quad_perm [2,3,2,3]  (broadcast u=1 per s)
// R13 BUG: row_shl:4 (0x104) moves data toward lane 0 (dest i <- src i+4,
// zero-fill from the right) — handed the f/o quad the WRONG cell's i*g.
// row_shr:4 (0x114) is the intended p=0 -> p=1 handoff: dest i <- src i-4.
#define DPP_SHR4 0x114  // row_shr:4            (p=0 quad -> p=1 quad)

#define CVT2(d0, d1, s) h2 d0 = h2{(_Float16)(s).x, (_Float16)(s).y}, \
                           d1 = h2{(_Float16)(s).z, (_Float16)(s).w};

// One block (512 thr) per batch element.
// lane = 16*rowgrp + 8*nn + 4*p + 2*u + s ; n = w*8 + rowgrp*2 + nn ;
// gate = p + 2u (p=0 quad: i,i,g,g ; p=1 quad: f,f,o,o), s = k-half (32 k).
//
// R9 (2087us, best) was DS-pipe bound: 64 invariant b128 h-broadcast reads +
// 16 ds_swizzle (gate gather) + small ops ~= 1252 cyc/step. R11 proved the
// MFMA/batched route is worse (activation work needs all 256 CUs). This
// round removes ALL swizzles: with gates quad-arranged, the cell update is
// pure DPP: ig = val*xor2(val) in the i/g quad, row_shr:4 hands it to the
// f/o quad, 0x44/0xEE broadcast f and o per s-lane. Cell state redundant in
// f/o-quad lanes; (p=1,u=0) lanes store h. Unused-lane garbage is bounded
// (acts<=1 -> no inf/NaN) and never stored.
//
// Layer pipelining (verified R3-R10): iter t computes L0 gates(t) from
// h0(t-1) and L1 gates(t-1) from {h1(t-2), h0(t-1)}; s=0 lanes run the L0
// act/cell path, s=1 the L1 path. 1 barrier/step, h fp16 double-buffered.
__global__ __launch_bounds__(512, 2)
void lstm2_fc_kernel(const float* __restrict__ x,      // [B, T, 1]
                     const float* __restrict__ W_ih0,  // [256, 1]
                     const float* __restrict__ W_hh0,  // [256, 64]
                     const float* __restrict__ b_ih0,  // [256]
                     const float* __restrict__ b_hh0,  // [256]
                     const float* __restrict__ W_ih1,  // [256, 64]
                     const float* __restrict__ W_hh1,  // [256, 64]
                     const float* __restrict__ b_ih1,  // [256]
                     const float* __restrict__ b_hh1,  // [256]
                     const float* __restrict__ W_fc,   // [128, 64]
                     const float* __restrict__ b_fc,   // [128]
                     float* __restrict__ out)          // [B, 128]
{
    const int b    = blockIdx.x;
    const int tid  = threadIdx.x;     // 0..511
    const int w    = tid >> 6;        // wave 0..7
    const int lane = tid & 63;
    const int ss   = lane & 1;        // k-half AND layer assignment
    const int uu   = (lane >> 1) & 1;
    const int pp   = (lane >> 2) & 1;
    const int nn   = (lane >> 3) & 1;
    const int n    = w * 8 + (lane >> 4) * 2 + nn;   // h-index 0..63
    const int gidx = pp + 2 * uu;                    // 0:i 1:f 2:g 3:o

    __shared__ float x_s[TT];                          // 16 KB
    __shared__ __align__(16) _Float16 hbuf[2][2 * HH]; // [parity][h0|h1], fp16

    for (int t = tid; t < TT; t += 512) x_s[t] = x[(size_t)b * TT + t];
    if (tid < 4 * HH) ((_Float16*)hbuf)[tid] = (_Float16)0.f;

    const int row = gidx * HH + n;   // gate row in [0,256)
    // --- Named-scalar weight load: 3 thirty-two-wide slices -> 48 h2 ---
    const float4* p0 = (const float4*)(W_hh0 + row * HH + ss * 32);
    const float4* p1 = (const float4*)(W_ih1 + row * HH + ss * 32);
    const float4* p2 = (const float4*)(W_hh1 + row * HH + ss * 32);
    float4 a0 = p0[0], a1 = p0[1], a2 = p0[2], a3 = p0[3];
    float4 a4 = p0[4], a5 = p0[5], a6 = p0[6], a7 = p0[7];
    float4 e0 = p1[0], e1 = p1[1], e2 = p1[2], e3 = p1[3];
    float4 e4 = p1[4], e5 = p1[5], e6 = p1[6], e7 = p1[7];
    float4 d0 = p2[0], d1 = p2[1], d2 = p2[2], d3 = p2[3];
    float4 d4 = p2[4], d5 = p2[5], d6 = p2[6], d7 = p2[7];
    CVT2(A0,  A1,  a0) CVT2(A2,  A3,  a1) CVT2(A4,  A5,  a2) CVT2(A6,  A7,  a3)
    CVT2(A8,  A9,  a4) CVT2(A10, A11, a5) CVT2(A12, A13, a6) CVT2(A14, A15, a7)
    CVT2(B0,  B1,  e0) CVT2(B2,  B3,  e1) CVT2(B4,  B5,  e2) CVT2(B6,  B7,  e3)
    CVT2(B8,  B9,  e4) CVT2(B10, B11, e5) CVT2(B12, B13, e6) CVT2(B14, B15, e7)
    CVT2(C0,  C1,  d0) CVT2(C2,  C3,  d1) CVT2(C4,  C5,  d2) CVT2(C6,  C7,  d3)
    CVT2(C8,  C9,  d4) CVT2(C10, C11, d5) CVT2(C12, C13, d6) CVT2(C14, C15, d7)

    float wx  = W_ih0[row];
    float bb0 = b_ih0[row] + b_hh0[row];
    float bb1 = b_ih1[row] + b_hh1[row];

    // Remat fences (R7/R9-proven).
    asm volatile("" : "+v"(A0), "+v"(A1), "+v"(A2),  "+v"(A3),
                      "+v"(A4), "+v"(A5), "+v"(A6),  "+v"(A7),
                      "+v"(A8), "+v"(A9), "+v"(A10), "+v"(A11),
                      "+v"(A12),"+v"(A13),"+v"(A14), "+v"(A15),
                      "+v"(B0), "+v"(B1), "+v"(B2),  "+v"(B3),
                      "+v"(B4), "+v"(B5), "+v"(B6),  "+v"(B7));
    asm volatile("" : "+v"(B8), "+v"(B9), "+v"(B10), "+v"(B11),
                      "+v"(B12),"+v"(B13),"+v"(B14), "+v"(B15),
                      "+v"(C0), "+v"(C1), "+v"(C2),  "+v"(C3),
                      "+v"(C4), "+v"(C5), "+v"(C6),  "+v"(C7),
                      "+v"(C8), "+v"(C9), "+v"(C10), "+v"(C11),
                      "+v"(C12),"+v"(C13),"+v"(C14), "+v"(C15),
                      "+v"(wx), "+v"(bb0),"+v"(bb1));

    // act(z) = mm * rcp(1 + exp(kk*z)) + aa ; tanh only for gate g (gidx==2).
    const bool isg = (gidx == 2);
    const float kk = isg ? -2.f : -1.f;
    const float mm = isg ?  2.f :  1.f;
    const float aa = isg ? -1.f :  0.f;

    const bool wlane = (pp == 1) && (uu == 0);   // h writers (f lanes)
    const int  hoff  = ss * HH + n;              // s=0 -> h0[n], s=1 -> h1[n]
    float cc = 0.f;                              // valid in p=1 lanes

    __syncthreads();

    for (int t = 0; t <= TT; ++t) {
        const float xt = x_s[(t < TT) ? t : 0];
        const h8* hb = (const h8*)hbuf[t & 1];
        // This lane's 32-half k-slices (2-addr broadcast b128, conflict-free).
        h8 Ha = hb[4 * ss + 0], Hc = hb[4 * ss + 1];
        h8 He = hb[4 * ss + 2], Hg = hb[4 * ss + 3];
        h8 Ga = hb[8 + 4 * ss + 0], Gc = hb[8 + 4 * ss + 1];
        h8 Ge = hb[8 + 4 * ss + 2], Gg = hb[8 + 4 * ss + 3];

        float acc0 = ss ? 0.f : fmaf(xt, wx, bb0);
        float acc1 = ss ? 0.f : bb1;
        acc0 = FDOT2(A0,  H2V(Ha, 0), acc0); acc0 = FDOT2(A1,  H2V(Ha, 1), acc0);
        acc0 = FDOT2(A2,  H2V(Ha, 2), acc0); acc0 = FDOT2(A3,  H2V(Ha, 3), acc0);
        acc0 = FDOT2(A4,  H2V(Hc, 0), acc0); acc0 = FDOT2(A5,  H2V(Hc, 1), acc0);
        acc0 = FDOT2(A6,  H2V(Hc, 2), acc0); acc0 = FDOT2(A7,  H2V(Hc, 3), acc0);
        acc0 = FDOT2(A8,  H2V(He, 0), acc0); acc0 = FDOT2(A9,  H2V(He, 1), acc0);
        acc0 = FDOT2(A10, H2V(He, 2), acc0); acc0 = FDOT2(A11, H2V(He, 3), acc0);
        acc0 = FDOT2(A12, H2V(Hg, 0), acc0); acc0 = FDOT2(A13, H2V(Hg, 1), acc0);
        acc0 = FDOT2(A14, H2V(Hg, 2), acc0); acc0 = FDOT2(A15, H2V(Hg, 3), acc0);

        acc1 = FDOT2(B0,  H2V(Ha, 0), acc1); acc1 = FDOT2(B1,  H2V(Ha, 1), acc1);
        acc1 = FDOT2(B2,  H2V(Ha, 2), acc1); acc1 = FDOT2(B3,  H2V(Ha, 3), acc1);
        acc1 = FDOT2(B4,  H2V(Hc, 0), acc1); acc1 = FDOT2(B5,  H2V(Hc, 1), acc1);
        acc1 = FDOT2(B6,  H2V(Hc, 2), acc1); acc1 = FDOT2(B7,  H2V(Hc, 3), acc1);
        acc1 = FDOT2(B8,  H2V(He, 0), acc1); acc1 = FDOT2(B9,  H2V(He, 1), acc1);
        acc1 = FDOT2(B10, H2V(He, 2), acc1); acc1 = FDOT2(B11, H2V(He, 3), acc1);
        acc1 = FDOT2(B12, H2V(Hg, 0), acc1); acc1 = FDOT2(B13, H2V(Hg, 1), acc1);
        acc1 = FDOT2(B14, H2V(Hg, 2), acc1); acc1 = FDOT2(B15, H2V(Hg, 3), acc1);
        acc1 = FDOT2(C0,  H2V(Ga, 0), acc1); acc1 = FDOT2(C1,  H2V(Ga, 1), acc1);
        acc1 = FDOT2(C2,  H2V(Ga, 2), acc1); acc1 = FDOT2(C3,  H2V(Ga, 3), acc1);
        acc1 = FDOT2(C4,  H2V(Gc, 0), acc1); acc1 = FDOT2(C5,  H2V(Gc, 1), acc1);
        acc1 = FDOT2(C6,  H2V(Gc, 2), acc1); acc1 = FDOT2(C7,  H2V(Gc, 3), acc1);
        acc1 = FDOT2(C8,  H2V(Ge, 0), acc1); acc1 = FDOT2(C9,  H2V(Ge, 1), acc1);
        acc1 = FDOT2(C10, H2V(Ge, 2), acc1); acc1 = FDOT2(C11, H2V(Ge, 3), acc1);
        acc1 = FDOT2(C12, H2V(Gg, 0), acc1); acc1 = FDOT2(C13, H2V(Gg, 1), acc1);
        acc1 = FDOT2(C14, H2V(Gg, 2), acc1); acc1 = FDOT2(C15, H2V(Gg, 3), acc1);

        // s-butterfly (DPP xor1): both s-lanes hold full row sums.
        acc0 += dpp_mov<DPP_XOR1>(acc0);
        acc1 += dpp_mov<DPP_XOR1>(acc1);

        // Per-lane layer: s=0 -> L0(t), s=1 -> L1(t-1). One activation each.
        float z  = ss ? acc1 : acc0;
        float ez = __expf(kk * z);
        float val = fmaf(mm, __builtin_amdgcn_rcpf(1.f + ez), aa);

        // Gate combine, all DPP:
        //  p=0 quad (i,i,g,g): ig = val * xor2(val)     [per s]
        //  row_shr:4 hands ig to the p=1 quad (f,f,o,o) [dest i <- src i-4]
        //  f/o broadcast per s via quad_perm 0x44/0xEE
        float igq = val * dpp_mov<DPP_XOR2>(val);
        float ig  = dpp_mov<DPP_SHR4>(igq);
        float fb  = dpp_mov<DPP_FB>(val);
        float ob  = dpp_mov<DPP_OB>(val);

        float cn = fmaf(fb, cc, ig);
        float hn = ob * ftanh(cn);
        bool ok = ss ? (t > 0) : (t < TT);       // L1 skip at 0, L0 at TT
        cc = ok ? cn : cc;
        if (wlane && ok) hbuf[(t + 1) & 1][hoff] = (_Float16)hn;

        __syncthreads();                         // h exchange (double-buffered)
    }

    // FC on final h1 = h1(TT-1), in hbuf[(TT+1)&1][64..128).
    if (tid < EE) {
        const _Float16* h1f = &hbuf[(TT + 1) & 1][HH];
        float acc = b_fc[tid];
        const float4* wf = (const float4*)(W_fc + tid * HH);
        #pragma unroll
        for (int k = 0; k < HH / 4; ++k) {
            float4 v = wf[k];
            acc = fmaf(v.x, (float)h1f[4*k+0], acc);
            acc = fmaf(v.y, (float)h1f[4*k+1], acc);
            acc = fmaf(v.z, (float)h1f[4*k+2], acc);
            acc = fmaf(v.w, (float)h1f[4*k+3], acc);
        }
        out[(size_t)b * EE + tid] = acc;
    }
}

extern "C" void kernel_launch(void* const* d_in, const int* in_sizes, int n_in,
                              void* d_out, int out_size, void* d_ws, size_t ws_size,
                              hipStream_t stream) {
    const float* x     = (const float*)d_in[0];
    const float* W_ih0 = (const float*)d_in[1];
    const float* W_hh0 = (const float*)d_in[2];
    const float* b_ih0 = (const float*)d_in[3];
    const float* b_hh0 = (const float*)d_in[4];
    const float* W_ih1 = (const float*)d_in[5];
    const float* W_hh1 = (const float*)d_in[6];
    const float* b_ih1 = (const float*)d_in[7];
    const float* b_hh1 = (const float*)d_in[8];
    const float* W_fc  = (const float*)d_in[9];
    const float* b_fc  = (const float*)d_in[10];
    float* out = (float*)d_out;

    lstm2_fc_kernel<<<dim3(NB), dim3(512), 0, stream>>>(
        x, W_ih0, W_hh0, b_ih0, b_hh0, W_ih1, W_hh1, b_ih1, b_hh1, W_fc, b_fc, out);
}